// Round 1
// baseline (41.622 us; speedup 1.0000x reference)
//
#include <hip/hip_runtime.h>
#include <cstddef>

// Problem constants (from setup_inputs): B=2, H=W=128, C=16, F=16, px=py=8, sx=sy=4
#define HH 128
#define WW 128
#define CC 16
#define FF 16

// Stage 1: per-patch per-channel per-basis normalization ratio.
// ratio[b, I, J, ch, f] = (sum_{window} pet*b) / (sum_{window} b), divide_no_nan.
// Window for patch (I,J): rows [4I-2, 4I+6), cols [4J-2, 4J+6), zero outside [0,128).
// 16 lanes per (b,I,J,ch) group; lane = f.
__global__ __launch_bounds__(256) void ratio_kernel(
    const float* __restrict__ pet,   // (B,128,128,16)
    const float* __restrict__ bfe,   // (B,128,128,16,16)
    float* __restrict__ ratio)       // (B,32,32,16,16)
{
    int t = blockIdx.x * 256 + threadIdx.x;
    int f  = t & 15;
    int g  = t >> 4;           // (b,I,J,ch) group id
    int ch = g & 15;
    int Jj = (g >> 4) & 31;
    int Ii = (g >> 9) & 31;
    int b  = g >> 14;

    int r0 = 4 * Ii - 2;
    int s0 = 4 * Jj - 2;
    float diag = 0.f, kp = 0.f;
    #pragma unroll
    for (int p = 0; p < 8; ++p) {
        int r = r0 + p;
        if ((unsigned)r >= (unsigned)HH) continue;
        #pragma unroll
        for (int q = 0; q < 8; ++q) {
            int s = s0 + q;
            if ((unsigned)s >= (unsigned)WW) continue;
            int pix = (b * HH + r) * WW + s;
            float bv = bfe[(size_t)pix * (CC * FF) + ch * FF + f];
            float pv = pet[(size_t)pix * CC + ch];
            diag += bv;
            kp   += pv * bv;
        }
    }
    float rv = (diag != 0.f) ? (kp / diag) : 0.f;
    ratio[(size_t)g * FF + f] = rv;
}

// Stage 2: out[b,y,x,ch] = 0.25 * sum_f bfe[b,y,x,ch,f] * (sum over valid (il,jl) of ratio[b,I,J,ch,f])
// il=0 valid iff y<=125; il=1 valid iff y>=2 (same for jl vs x). I = 2*((y+2-4*il)>>3)+il.
__global__ __launch_bounds__(256) void out_kernel(
    const float* __restrict__ bfe,   // (B,128,128,16,16)
    const float* __restrict__ ratio, // (B,32,32,16,16)
    float* __restrict__ out)         // (B,128,128,16)
{
    int t  = blockIdx.x * 256 + threadIdx.x;
    int ch = t & 15;
    int x  = (t >> 4) & 127;
    int y  = (t >> 11) & 127;
    int b  = t >> 18;

    float rs[16];
    #pragma unroll
    for (int i = 0; i < 16; ++i) rs[i] = 0.f;

    #pragma unroll
    for (int il = 0; il < 2; ++il) {
        bool vy = il ? (y >= 2) : (y <= 125);
        int Yv = y + 2 - 4 * il;
        int I  = 2 * (Yv >> 3) + il;
        #pragma unroll
        for (int jl = 0; jl < 2; ++jl) {
            bool vx = jl ? (x >= 2) : (x <= 125);
            int Xv = x + 2 - 4 * jl;
            int J  = 2 * (Xv >> 3) + jl;
            if (vy && vx) {
                const float4* rp = (const float4*)(ratio +
                    (size_t)(((b * 32 + I) * 32 + J) * CC + ch) * FF);
                #pragma unroll
                for (int v = 0; v < 4; ++v) {
                    float4 rv = rp[v];
                    rs[4*v+0] += rv.x; rs[4*v+1] += rv.y;
                    rs[4*v+2] += rv.z; rs[4*v+3] += rv.w;
                }
            }
        }
    }

    const float4* bp = (const float4*)(bfe +
        (size_t)((b * HH + y) * WW + x) * (CC * FF) + (size_t)ch * FF);
    float acc = 0.f;
    #pragma unroll
    for (int v = 0; v < 4; ++v) {
        float4 bv = bp[v];
        acc += rs[4*v+0] * bv.x + rs[4*v+1] * bv.y
             + rs[4*v+2] * bv.z + rs[4*v+3] * bv.w;
    }
    out[t] = 0.25f * acc;
}

extern "C" void kernel_launch(void* const* d_in, const int* in_sizes, int n_in,
                              void* d_out, int out_size, void* d_ws, size_t ws_size,
                              hipStream_t stream) {
    // inputs: 0=mr (unused), 1=pet (B,128,128,16), 2=b_features (B,128,128,16,16),
    //         3..6 = px,py,sx,sy scalars (hard-coded: 8,8,4,4)
    const float* pet = (const float*)d_in[1];
    const float* bfe = (const float*)d_in[2];
    float* ratio = (float*)d_ws;       // needs B*32*32*16*16*4 = 2 MB
    float* out   = (float*)d_out;

    int B = in_sizes[1] / (HH * WW * CC);   // = 2

    int g1 = (B * 32 * 32 * CC * FF) / 256; // 2048 blocks
    ratio_kernel<<<g1, 256, 0, stream>>>(pet, bfe, ratio);

    int g2 = (B * HH * WW * CC) / 256;      // 2048 blocks
    out_kernel<<<g2, 256, 0, stream>>>(bfe, ratio, out);
}

// Round 2
// 29.909 us; speedup vs baseline: 1.3916x; 1.3916x over previous
//
#include <hip/hip_runtime.h>
#include <cstddef>

// Problem constants: B=2, H=W=128, C=16, F=16, px=py=8, sx=sy=4 -> lx=ly=2
#define HH 128
#define WW 128
#define CC 16
#define FF 16
#define NCELL 33   // cells per dim (boundaries at 4k-2)
#define NW 32      // windows (patches) per dim

// ---------------------------------------------------------------------------
// Kernel A: per-cell partial sums. Cell (i,j) covers rows [4i-2,4i+2) x cols
// [4j-2,4j+2), clipped to [0,128). Each 8x8 window (I,J) = cells {I,I+1}x{J,J+1}.
// cellD/cellK layout: [b][i][j][ch][f] as float4 over f (index = thread id t).
// Thread: f4=t&3 (4 f-values), ch=(t>>2)&15, then j,i,b.
// ---------------------------------------------------------------------------
__global__ __launch_bounds__(256) void cell_kernel(
    const float* __restrict__ pet,    // (B,128,128,16)
    const float4* __restrict__ bfe4,  // (B,128,128,16,16) viewed as float4 over f
    float4* __restrict__ cellD,
    float4* __restrict__ cellK,
    int total)
{
    int t = blockIdx.x * 256 + threadIdx.x;
    if (t >= total) return;
    int f4  = t & 3;
    int ch  = (t >> 2) & 15;
    int rest = t >> 6;          // (b*33 + i)*33 + j, range [0, 2*33*33)
    int j   = rest % NCELL;
    int tmp = rest / NCELL;
    int i   = tmp % NCELL;
    int b   = tmp / NCELL;

    int r0 = 4 * i - 2;
    int s0 = 4 * j - 2;
    float4 d = make_float4(0.f, 0.f, 0.f, 0.f);
    float4 k = make_float4(0.f, 0.f, 0.f, 0.f);
    #pragma unroll
    for (int p = 0; p < 4; ++p) {
        int r = r0 + p;
        if ((unsigned)r >= (unsigned)HH) continue;
        #pragma unroll
        for (int q = 0; q < 4; ++q) {
            int s = s0 + q;
            if ((unsigned)s >= (unsigned)WW) continue;
            int pix = (b * HH + r) * WW + s;
            float4 bv = bfe4[(size_t)pix * (CC * FF / 4) + ch * 4 + f4];
            float  pv = pet[(size_t)pix * CC + ch];
            d.x += bv.x;      d.y += bv.y;      d.z += bv.z;      d.w += bv.w;
            k.x += pv * bv.x; k.y += pv * bv.y; k.z += pv * bv.z; k.w += pv * bv.w;
        }
    }
    cellD[t] = d;
    cellK[t] = k;
}

// ---------------------------------------------------------------------------
// Kernel B: window sums from 4 cells + divide_no_nan -> ratio[b][I][J][ch][f]
// (float4 over f, index = t). Thread: f4=t&3, ch=(t>>2)&15, J=(t>>6)&31,
// I=(t>>11)&31, b=t>>16.
// ---------------------------------------------------------------------------
__global__ __launch_bounds__(256) void ratio_kernel(
    const float4* __restrict__ cellD,
    const float4* __restrict__ cellK,
    float4* __restrict__ ratio)
{
    int t  = blockIdx.x * 256 + threadIdx.x;
    int f4 = t & 3;
    int ch = (t >> 2) & 15;
    int J  = (t >> 6) & 31;
    int I  = (t >> 11) & 31;
    int b  = t >> 16;

    float4 D = make_float4(0.f, 0.f, 0.f, 0.f);
    float4 K = make_float4(0.f, 0.f, 0.f, 0.f);
    #pragma unroll
    for (int di = 0; di < 2; ++di) {
        #pragma unroll
        for (int dj = 0; dj < 2; ++dj) {
            size_t c = ((((size_t)b * NCELL + (I + di)) * NCELL + (J + dj)) * CC + ch) * 4 + f4;
            float4 cd = cellD[c];
            float4 ck = cellK[c];
            D.x += cd.x; D.y += cd.y; D.z += cd.z; D.w += cd.w;
            K.x += ck.x; K.y += ck.y; K.z += ck.z; K.w += ck.w;
        }
    }
    float4 rv;
    rv.x = (D.x != 0.f) ? K.x / D.x : 0.f;
    rv.y = (D.y != 0.f) ? K.y / D.y : 0.f;
    rv.z = (D.z != 0.f) ? K.z / D.z : 0.f;
    rv.w = (D.w != 0.f) ? K.w / D.w : 0.f;
    ratio[t] = rv;
}

// ---------------------------------------------------------------------------
// Kernel C: out[b,y,x,ch] = 0.25 * sum_f bfe[b,y,x,ch,f] *
//   (sum over valid (il,jl) of ratio[b,I,J,ch,f]);
// il=0 valid iff y<=125, il=1 iff y>=2 (same for jl/x); I=2*((y+2-4il)>>3)+il.
// ---------------------------------------------------------------------------
__global__ __launch_bounds__(256) void out_kernel(
    const float* __restrict__ bfe,
    const float* __restrict__ ratio,
    float* __restrict__ out)
{
    int t  = blockIdx.x * 256 + threadIdx.x;
    int ch = t & 15;
    int x  = (t >> 4) & 127;
    int y  = (t >> 11) & 127;
    int b  = t >> 18;

    float rs[16];
    #pragma unroll
    for (int i = 0; i < 16; ++i) rs[i] = 0.f;

    #pragma unroll
    for (int il = 0; il < 2; ++il) {
        bool vy = il ? (y >= 2) : (y <= 125);
        int Yv = y + 2 - 4 * il;
        int I  = 2 * (Yv >> 3) + il;
        #pragma unroll
        for (int jl = 0; jl < 2; ++jl) {
            bool vx = jl ? (x >= 2) : (x <= 125);
            int Xv = x + 2 - 4 * jl;
            int J  = 2 * (Xv >> 3) + jl;
            if (vy && vx) {
                const float4* rp = (const float4*)(ratio +
                    (size_t)(((b * 32 + I) * 32 + J) * CC + ch) * FF);
                #pragma unroll
                for (int v = 0; v < 4; ++v) {
                    float4 rv = rp[v];
                    rs[4*v+0] += rv.x; rs[4*v+1] += rv.y;
                    rs[4*v+2] += rv.z; rs[4*v+3] += rv.w;
                }
            }
        }
    }

    const float4* bp = (const float4*)(bfe +
        (size_t)((b * HH + y) * WW + x) * (CC * FF) + (size_t)ch * FF);
    float acc = 0.f;
    #pragma unroll
    for (int v = 0; v < 4; ++v) {
        float4 bv = bp[v];
        acc += rs[4*v+0] * bv.x + rs[4*v+1] * bv.y
             + rs[4*v+2] * bv.z + rs[4*v+3] * bv.w;
    }
    out[t] = 0.25f * acc;
}

extern "C" void kernel_launch(void* const* d_in, const int* in_sizes, int n_in,
                              void* d_out, int out_size, void* d_ws, size_t ws_size,
                              hipStream_t stream) {
    // inputs: 0=mr (unused), 1=pet (B,128,128,16), 2=b_features (B,128,128,16,16)
    const float* pet = (const float*)d_in[1];
    const float* bfe = (const float*)d_in[2];
    int B = in_sizes[1] / (HH * WW * CC);   // = 2

    // workspace layout (float4 units)
    int nCellVec = B * NCELL * NCELL * CC * FF / 4;   // 139392 for B=2
    int nWinVec  = B * NW * NW * CC * FF / 4;         // 131072 for B=2
    float4* cellD = (float4*)d_ws;
    float4* cellK = cellD + nCellVec;
    float4* ratio = cellK + nCellVec;

    int totalA = nCellVec;                    // one thread per float4 cell slot
    int gA = (totalA + 255) / 256;            // 545 blocks
    cell_kernel<<<gA, 256, 0, stream>>>(pet, (const float4*)bfe, cellD, cellK, totalA);

    int gB = nWinVec / 256;                   // 512 blocks
    ratio_kernel<<<gB, 256, 0, stream>>>(cellD, cellK, ratio);

    int gC = (B * HH * WW * CC) / 256;        // 2048 blocks
    out_kernel<<<gC, 256, 0, stream>>>(bfe, (const float*)ratio, (float*)d_out);
}

// Round 3
// 28.111 us; speedup vs baseline: 1.4807x; 1.0640x over previous
//
#include <hip/hip_runtime.h>
#include <cstddef>

// Problem constants: B=2, H=W=128, C=16, F=16, px=py=8, sx=sy=4 -> lx=ly=2
#define HH 128
#define WW 128
#define CC 16
#define FF 16

// Fully fused kernel. Block = (b, ch, 16x16 pixel tile). 256 threads.
// Phase 1: 7x7 halo cells (4x4 non-overlapping partial sums of b and pet*b)
//          -> LDS.  Cell gi covers rows [4*gi-2, 4*gi+2), zero-clipped.
// Phase 2: 6x6 patch ratios (divide_no_nan of 2x2-cell window sums) -> LDS.
// Phase 3: out[b,y,x,ch] = 0.25 * sum_f bfe[...,f] * (sum of <=4 valid ratios).
//   il=0 valid iff y<=125 (local pi = 2*((dy+2)>>3)+1),
//   il=1 valid iff y>=2   (local pi = 2*((dy-2)>>3)+2, arithmetic shift).
__global__ __launch_bounds__(256) void fused_kernel(
    const float*  __restrict__ pet,   // (B,128,128,16)
    const float4* __restrict__ bfe4,  // (B,128,128,16,16) as float4 over f
    float* __restrict__ out)          // (B,128,128,16)
{
    // LDS: cells 7x7 x 4 float4 (D and K), ratios 6x6 x 4 float4
    __shared__ float4 sD[7 * 7 * 4];   // 3136 B
    __shared__ float4 sK[7 * 7 * 4];   // 3136 B
    __shared__ float4 sR[6 * 6 * 4];   // 2304 B

    int bid = blockIdx.x;
    int tx = bid & 7;
    int ty = (bid >> 3) & 7;
    int ch = (bid >> 6) & 15;
    int b  = bid >> 10;

    int tid = threadIdx.x;
    int y0 = 16 * ty, x0 = 16 * tx;
    int gi0 = 4 * ty - 1, gj0 = 4 * tx - 1;   // global cell origin

    // ---------------- Phase 1: cells ----------------
    if (tid < 196) {                 // 7*7 cells * 4 f4-groups = 196 items
        int f4 = tid & 3;
        int cc = tid >> 2;           // 0..48
        int cj = cc % 7, ci = cc / 7;
        int r0 = 4 * (gi0 + ci) - 2;
        int s0 = 4 * (gj0 + cj) - 2;
        float4 d = make_float4(0.f, 0.f, 0.f, 0.f);
        float4 k = make_float4(0.f, 0.f, 0.f, 0.f);
        #pragma unroll
        for (int p = 0; p < 4; ++p) {
            int r = r0 + p;
            if ((unsigned)r >= (unsigned)HH) continue;
            #pragma unroll
            for (int q = 0; q < 4; ++q) {
                int s = s0 + q;
                if ((unsigned)s >= (unsigned)WW) continue;
                int pix = (b * HH + r) * WW + s;
                float4 bv = bfe4[(size_t)pix * 64 + ch * 4 + f4];
                float  pv = pet[(size_t)pix * CC + ch];
                d.x += bv.x;      d.y += bv.y;      d.z += bv.z;      d.w += bv.w;
                k.x += pv * bv.x; k.y += pv * bv.y; k.z += pv * bv.z; k.w += pv * bv.w;
            }
        }
        sD[cc * 4 + f4] = d;
        sK[cc * 4 + f4] = k;
    }
    __syncthreads();

    // ---------------- Phase 2: ratios ----------------
    if (tid < 144) {                 // 6*6 patches * 4 = 144 items
        int f4 = tid & 3;
        int pc = tid >> 2;           // 0..35
        int pj = pc % 6, pi = pc / 6;
        float4 D = make_float4(0.f, 0.f, 0.f, 0.f);
        float4 K = make_float4(0.f, 0.f, 0.f, 0.f);
        #pragma unroll
        for (int di = 0; di < 2; ++di) {
            #pragma unroll
            for (int dj = 0; dj < 2; ++dj) {
                int cc = (pi + di) * 7 + (pj + dj);
                float4 cd = sD[cc * 4 + f4];
                float4 ck = sK[cc * 4 + f4];
                D.x += cd.x; D.y += cd.y; D.z += cd.z; D.w += cd.w;
                K.x += ck.x; K.y += ck.y; K.z += ck.z; K.w += ck.w;
            }
        }
        float4 rv;
        rv.x = (D.x != 0.f) ? K.x / D.x : 0.f;
        rv.y = (D.y != 0.f) ? K.y / D.y : 0.f;
        rv.z = (D.z != 0.f) ? K.z / D.z : 0.f;
        rv.w = (D.w != 0.f) ? K.w / D.w : 0.f;
        sR[pc * 4 + f4] = rv;
    }
    __syncthreads();

    // ---------------- Phase 3: output ----------------
    int dy = tid >> 4, dx = tid & 15;
    int y = y0 + dy, x = x0 + dx;

    float rs[16];
    #pragma unroll
    for (int i = 0; i < 16; ++i) rs[i] = 0.f;

    #pragma unroll
    for (int il = 0; il < 2; ++il) {
        bool vy = il ? (y >= 2) : (y <= 125);
        int pi = il ? (2 * ((dy - 2) >> 3) + 2)    // arithmetic shift ok
                    : (2 * ((dy + 2) >> 3) + 1);
        #pragma unroll
        for (int jl = 0; jl < 2; ++jl) {
            bool vx = jl ? (x >= 2) : (x <= 125);
            int pj = jl ? (2 * ((dx - 2) >> 3) + 2)
                        : (2 * ((dx + 2) >> 3) + 1);
            if (vy && vx) {
                int base = (pi * 6 + pj) * 4;
                #pragma unroll
                for (int v = 0; v < 4; ++v) {
                    float4 rv = sR[base + v];
                    rs[4*v+0] += rv.x; rs[4*v+1] += rv.y;
                    rs[4*v+2] += rv.z; rs[4*v+3] += rv.w;
                }
            }
        }
    }

    int pix = (b * HH + y) * WW + x;
    const float4* bp = bfe4 + (size_t)pix * 64 + ch * 4;
    float acc = 0.f;
    #pragma unroll
    for (int v = 0; v < 4; ++v) {
        float4 bv = bp[v];
        acc += rs[4*v+0] * bv.x + rs[4*v+1] * bv.y
             + rs[4*v+2] * bv.z + rs[4*v+3] * bv.w;
    }
    out[(size_t)pix * CC + ch] = 0.25f * acc;
}

extern "C" void kernel_launch(void* const* d_in, const int* in_sizes, int n_in,
                              void* d_out, int out_size, void* d_ws, size_t ws_size,
                              hipStream_t stream) {
    // inputs: 0=mr (unused), 1=pet (B,128,128,16), 2=b_features (B,128,128,16,16)
    const float* pet = (const float*)d_in[1];
    const float* bfe = (const float*)d_in[2];
    int B = in_sizes[1] / (HH * WW * CC);   // = 2

    // grid: b * ch * (8x8 tiles of 16x16) = B*16*64
    int grid = B * 16 * 64;                 // 2048 for B=2
    fused_kernel<<<grid, 256, 0, stream>>>(pet, (const float4*)bfe, (float*)d_out);
}

// Round 4
// 24.770 us; speedup vs baseline: 1.6803x; 1.1349x over previous
//
#include <hip/hip_runtime.h>
#include <cstddef>

// Problem constants: B=2, H=W=128, C=16, F=16, px=py=8, sx=sy=4 -> lx=ly=2
#define HH 128
#define WW 128
#define CC 16
#define FF 16
#define NCELL 33   // global cell grid per dim; cell k covers rows [4k-2, 4k+2)

// ---------------------------------------------------------------------------
// K1: per-cell partial sums, each cell computed exactly once globally.
// cellD/cellK layout (float4 units): ((b*33+i)*33+j)*64 + ch*4 + f4
// ---------------------------------------------------------------------------
__global__ __launch_bounds__(256) void cell_kernel(
    const float* __restrict__ pet,    // (B,128,128,16)
    const float4* __restrict__ bfe4,  // (B,128,128,16,16) as float4 over f
    float4* __restrict__ cellD,
    float4* __restrict__ cellK,
    int total)
{
    int t = blockIdx.x * 256 + threadIdx.x;
    if (t >= total) return;
    int f4  = t & 3;
    int ch  = (t >> 2) & 15;
    int rest = t >> 6;          // (b*33 + i)*33 + j
    int j   = rest % NCELL;
    int tmp = rest / NCELL;
    int i   = tmp % NCELL;
    int b   = tmp / NCELL;

    int r0 = 4 * i - 2;
    int s0 = 4 * j - 2;
    float4 d = make_float4(0.f, 0.f, 0.f, 0.f);
    float4 k = make_float4(0.f, 0.f, 0.f, 0.f);
    #pragma unroll
    for (int p = 0; p < 4; ++p) {
        int r = r0 + p;
        if ((unsigned)r >= (unsigned)HH) continue;
        #pragma unroll
        for (int q = 0; q < 4; ++q) {
            int s = s0 + q;
            if ((unsigned)s >= (unsigned)WW) continue;
            int pix = (b * HH + r) * WW + s;
            float4 bv = bfe4[(size_t)pix * 64 + ch * 4 + f4];
            float  pv = pet[(size_t)pix * CC + ch];
            d.x += bv.x;      d.y += bv.y;      d.z += bv.z;      d.w += bv.w;
            k.x += pv * bv.x; k.y += pv * bv.y; k.z += pv * bv.z; k.w += pv * bv.w;
        }
    }
    cellD[t] = d;
    cellK[t] = k;
}

// ---------------------------------------------------------------------------
// K2: fused ratio + output. Block = (b, ch, 16x16 tile), 256 threads.
// Phase 1': stage 7x7 precomputed cells from global into LDS (zeros outside
//           the 33x33 grid). Phase 2: 6x6 ratios. Phase 3: output pixels.
// ---------------------------------------------------------------------------
__global__ __launch_bounds__(256) void fused2_kernel(
    const float4* __restrict__ bfe4,
    const float4* __restrict__ cellD,
    const float4* __restrict__ cellK,
    float* __restrict__ out)
{
    __shared__ float4 sD[7 * 7 * 4];
    __shared__ float4 sK[7 * 7 * 4];
    __shared__ float4 sR[6 * 6 * 4];

    int bid = blockIdx.x;
    int tx = bid & 7;
    int ty = (bid >> 3) & 7;
    int ch = (bid >> 6) & 15;
    int b  = bid >> 10;

    int tid = threadIdx.x;
    int y0 = 16 * ty, x0 = 16 * tx;

    // ---------------- Phase 1': stage cells ----------------
    if (tid < 196) {                 // 49 cells * 4 f4-groups
        int f4 = tid & 3;
        int cc = tid >> 2;
        int cj = cc % 7, ci = cc / 7;
        int gi = 4 * ty - 1 + ci;    // [-1, 33]
        int gj = 4 * tx - 1 + cj;
        float4 d = make_float4(0.f, 0.f, 0.f, 0.f);
        float4 k = make_float4(0.f, 0.f, 0.f, 0.f);
        if ((unsigned)gi < (unsigned)NCELL && (unsigned)gj < (unsigned)NCELL) {
            size_t c = ((((size_t)b * NCELL + gi) * NCELL + gj) * CC + ch) * 4 + f4;
            d = cellD[c];
            k = cellK[c];
        }
        sD[tid] = d;                 // index cc*4+f4 == tid
        sK[tid] = k;
    }
    __syncthreads();

    // ---------------- Phase 2: ratios ----------------
    if (tid < 144) {                 // 36 patches * 4
        int f4 = tid & 3;
        int pc = tid >> 2;
        int pj = pc % 6, pi = pc / 6;
        float4 D = make_float4(0.f, 0.f, 0.f, 0.f);
        float4 K = make_float4(0.f, 0.f, 0.f, 0.f);
        #pragma unroll
        for (int di = 0; di < 2; ++di) {
            #pragma unroll
            for (int dj = 0; dj < 2; ++dj) {
                int cc = (pi + di) * 7 + (pj + dj);
                float4 cd = sD[cc * 4 + f4];
                float4 ck = sK[cc * 4 + f4];
                D.x += cd.x; D.y += cd.y; D.z += cd.z; D.w += cd.w;
                K.x += ck.x; K.y += ck.y; K.z += ck.z; K.w += ck.w;
            }
        }
        float4 rv;
        rv.x = (D.x != 0.f) ? K.x / D.x : 0.f;
        rv.y = (D.y != 0.f) ? K.y / D.y : 0.f;
        rv.z = (D.z != 0.f) ? K.z / D.z : 0.f;
        rv.w = (D.w != 0.f) ? K.w / D.w : 0.f;
        sR[pc * 4 + f4] = rv;
    }
    __syncthreads();

    // ---------------- Phase 3: output ----------------
    int dy = tid >> 4, dx = tid & 15;
    int y = y0 + dy, x = x0 + dx;

    float rs[16];
    #pragma unroll
    for (int i = 0; i < 16; ++i) rs[i] = 0.f;

    #pragma unroll
    for (int il = 0; il < 2; ++il) {
        bool vy = il ? (y >= 2) : (y <= 125);
        int pi = il ? (2 * ((dy - 2) >> 3) + 2)
                    : (2 * ((dy + 2) >> 3) + 1);
        #pragma unroll
        for (int jl = 0; jl < 2; ++jl) {
            bool vx = jl ? (x >= 2) : (x <= 125);
            int pj = jl ? (2 * ((dx - 2) >> 3) + 2)
                        : (2 * ((dx + 2) >> 3) + 1);
            if (vy && vx) {
                int base = (pi * 6 + pj) * 4;
                #pragma unroll
                for (int v = 0; v < 4; ++v) {
                    float4 rv = sR[base + v];
                    rs[4*v+0] += rv.x; rs[4*v+1] += rv.y;
                    rs[4*v+2] += rv.z; rs[4*v+3] += rv.w;
                }
            }
        }
    }

    int pix = (b * HH + y) * WW + x;
    const float4* bp = bfe4 + (size_t)pix * 64 + ch * 4;
    float acc = 0.f;
    #pragma unroll
    for (int v = 0; v < 4; ++v) {
        float4 bv = bp[v];
        acc += rs[4*v+0] * bv.x + rs[4*v+1] * bv.y
             + rs[4*v+2] * bv.z + rs[4*v+3] * bv.w;
    }
    out[(size_t)pix * CC + ch] = 0.25f * acc;
}

extern "C" void kernel_launch(void* const* d_in, const int* in_sizes, int n_in,
                              void* d_out, int out_size, void* d_ws, size_t ws_size,
                              hipStream_t stream) {
    // inputs: 0=mr (unused), 1=pet (B,128,128,16), 2=b_features (B,128,128,16,16)
    const float* pet = (const float*)d_in[1];
    const float* bfe = (const float*)d_in[2];
    int B = in_sizes[1] / (HH * WW * CC);   // = 2

    int nCellVec = B * NCELL * NCELL * CC * FF / 4;   // 139392 float4 for B=2
    float4* cellD = (float4*)d_ws;
    float4* cellK = cellD + nCellVec;

    int gA = (nCellVec + 255) / 256;          // 545 blocks
    cell_kernel<<<gA, 256, 0, stream>>>(pet, (const float4*)bfe, cellD, cellK, nCellVec);

    int grid = B * 16 * 64;                   // 2048 blocks
    fused2_kernel<<<grid, 256, 0, stream>>>((const float4*)bfe, cellD, cellK, (float*)d_out);
}